// Round 18
// baseline (601.146 us; speedup 1.0000x reference)
//
#include <hip/hip_runtime.h>
#include <hip/hip_bf16.h>
#include <math.h>

#define EDGES 800000
#define NNODES 100000
#define NGRAPH 1024

typedef __attribute__((ext_vector_type(8))) short short8v;
typedef __attribute__((ext_vector_type(4))) float float4v;
typedef unsigned short ushort_t;

__device__ inline ushort_t f2bf(float f) {
  __hip_bfloat16 h = __float2bfloat16(f);
  return *reinterpret_cast<ushort_t*>(&h);
}
__device__ inline float bf2f(ushort_t u) {
  return __uint_as_float(((unsigned int)u) << 16);
}

// ---------------- CSR build (bucketed, LDS-local) ----------------
#define NBMAX 512

__global__ __launch_bounds__(256) void bcount_k(const int* __restrict__ dst,
                                                int* __restrict__ bcnt, int E,
                                                int NB) {
  __shared__ int hist[NBMAX];
  int t = threadIdx.x;
  for (int b = t; b < NB; b += 256) hist[b] = 0;
  __syncthreads();
  int e0 = blockIdx.x * 4096;
  int e1 = min(E, e0 + 4096);
  for (int e = e0 + t; e < e1; e += 256) atomicAdd(&hist[dst[e] >> 8], 1);
  __syncthreads();
  for (int b = t; b < NB; b += 256)
    if (hist[b] > 0) atomicAdd(&bcnt[b], hist[b]);
}

// block 0: exclusive scan of bucket counts -> boff; blocks >=1: gstart binary search
__global__ __launch_bounds__(512) void scan_gstart_k(const int* __restrict__ bcnt,
                                                     int* __restrict__ boff, int NB,
                                                     const int* __restrict__ bat,
                                                     int* __restrict__ gs, int N,
                                                     int B) {
  int t = threadIdx.x;
  if (blockIdx.x == 0) {
    __shared__ int tmp[512];
    int v = (t < NB) ? bcnt[t] : 0;
    tmp[t] = v;
    __syncthreads();
    for (int off = 1; off < 512; off <<= 1) {
      int x = (t >= off) ? tmp[t - off] : 0;
      __syncthreads();
      tmp[t] += x;
      __syncthreads();
    }
    if (t < NB) boff[t] = tmp[t] - v;
    if (t == NB - 1) boff[NB] = tmp[t];
  } else {
    int g = (blockIdx.x - 1) * 512 + t;
    if (g > B) return;
    if (g == B) {
      gs[B] = N;
      return;
    }
    int lo = 0, hi = N;
    while (lo < hi) {
      int mid = (lo + hi) >> 1;
      if (bat[mid] < g) lo = mid + 1;
      else hi = mid;
    }
    gs[g] = lo;
  }
}

__global__ __launch_bounds__(256) void bscatter_k(const int* __restrict__ src,
                                                  const int* __restrict__ dst,
                                                  const int* __restrict__ boff,
                                                  int* __restrict__ bcur,
                                                  int2* __restrict__ EB, int E,
                                                  int NB) {
  __shared__ int hist[NBMAX], run[NBMAX], lcur[NBMAX];
  int t = threadIdx.x;
  for (int b = t; b < NB; b += 256) {
    hist[b] = 0;
    lcur[b] = 0;
  }
  __syncthreads();
  int e0 = blockIdx.x * 4096;
  int e1 = min(E, e0 + 4096);
  for (int e = e0 + t; e < e1; e += 256) atomicAdd(&hist[dst[e] >> 8], 1);
  __syncthreads();
  for (int b = t; b < NB; b += 256)
    if (hist[b] > 0) run[b] = atomicAdd(&bcur[b], hist[b]);
  __syncthreads();
  for (int e = e0 + t; e < e1; e += 256) {
    int d = dst[e];
    int b = d >> 8;
    int l = atomicAdd(&lcur[b], 1);
    int pos = boff[b] + run[b] + l;
    EB[pos] = make_int2(src[e], d);
  }
}

__global__ __launch_bounds__(256) void bucket_csr_k(const int2* __restrict__ EB,
                                                    const int* __restrict__ boff,
                                                    int* __restrict__ rowstart,
                                                    int* __restrict__ adj, int N,
                                                    int NB, int E) {
  __shared__ int cnt[256], pfx[256], lcur[256];
  int b = blockIdx.x, t = threadIdx.x;
  int e0 = boff[b], e1 = boff[b + 1];
  cnt[t] = 0;
  __syncthreads();
  for (int e = e0 + t; e < e1; e += 256) atomicAdd(&cnt[EB[e].y & 255], 1);
  __syncthreads();
  int v = cnt[t];
  pfx[t] = v;
  __syncthreads();
  for (int off = 1; off < 256; off <<= 1) {
    int x = (t >= off) ? pfx[t - off] : 0;
    __syncthreads();
    pfx[t] += x;
    __syncthreads();
  }
  int node = (b << 8) + t;
  if (node < N) rowstart[node] = e0 + pfx[t] - v;
  if (b == NB - 1 && t == 0) rowstart[N] = E;
  lcur[t] = 0;
  __syncthreads();
  for (int e = e0 + t; e < e1; e += 256) {
    int2 ed = EB[e];
    int ln = ed.y & 255;
    int l = atomicAdd(&lcur[ln], 1);
    adj[e0 + pfx[ln] - cnt[ln] + l] = ed.x;
  }
}

// ---------------- branch-start zero: BC + XA pad rows + SSQ ----------------
__global__ __launch_bounds__(256) void bzero_k(int* __restrict__ BC, int nBC,
                                               ushort_t* __restrict__ pad, long npad,
                                               float* __restrict__ ssq) {
  long i = (long)blockIdx.x * 256 + threadIdx.x;
  if (i < nBC) BC[i] = 0;
  if (i < npad) pad[i] = 0;
  if (i < 2) ssq[i] = 0.f;
}

// ---------------- f32 -> padded bf16 ----------------
template <int KP>
__global__ __launch_bounds__(256) void tobf16_k(const float* __restrict__ x,
                                                ushort_t* __restrict__ out, int M,
                                                int F) {
  long i = (long)blockIdx.x * 256 + threadIdx.x;
  if (i >= (long)M * KP) return;
  int r = (int)(i / KP), c = (int)(i % KP);
  float v = (c < F) ? x[(long)r * F + c] : 0.f;
  out[i] = f2bf(v);
}

// ---------------- gather: out[i] = X[i] + sum_{j in nbr(i)} X[j]  (bf16) ----------------
template <int KP>
__global__ __launch_bounds__(256) void gather_k(const ushort_t* __restrict__ X,
                                                const int* __restrict__ rowstart,
                                                const int* __restrict__ adj,
                                                ushort_t* __restrict__ out, int M) {
  constexpr int CH = KP / 8;
  long tid = (long)blockIdx.x * 256 + threadIdx.x;
  if (tid >= (long)M * CH) return;
  int node = (int)(tid / CH), ch = (int)(tid % CH);
  int o = ch * 8;
  float acc[8];
  uint4 self = *(const uint4*)&X[(long)node * KP + o];
  {
    const unsigned int u[4] = {self.x, self.y, self.z, self.w};
#pragma unroll
    for (int i = 0; i < 4; ++i) {
      acc[2 * i] = __uint_as_float((u[i] & 0xFFFFu) << 16);
      acc[2 * i + 1] = __uint_as_float(u[i] & 0xFFFF0000u);
    }
  }
  auto add4 = [&](uint4 v) {
    const unsigned int u[4] = {v.x, v.y, v.z, v.w};
#pragma unroll
    for (int i = 0; i < 4; ++i) {
      acc[2 * i] += __uint_as_float((u[i] & 0xFFFFu) << 16);
      acc[2 * i + 1] += __uint_as_float(u[i] & 0xFFFF0000u);
    }
  };
  int rs = rowstart[node], re = rowstart[node + 1];
  int e = rs;
  for (; e + 4 <= re; e += 4) {
    int j0 = adj[e], j1 = adj[e + 1], j2 = adj[e + 2], j3 = adj[e + 3];
    uint4 v0 = *(const uint4*)&X[(long)j0 * KP + o];
    uint4 v1 = *(const uint4*)&X[(long)j1 * KP + o];
    uint4 v2 = *(const uint4*)&X[(long)j2 * KP + o];
    uint4 v3 = *(const uint4*)&X[(long)j3 * KP + o];
    add4(v0);
    add4(v1);
    add4(v2);
    add4(v3);
  }
  for (; e < re; ++e) {
    int j = adj[e];
    add4(*(const uint4*)&X[(long)j * KP + o]);
  }
  uint4 r;
  unsigned int* p = &r.x;
#pragma unroll
  for (int i = 0; i < 4; ++i) {
    unsigned int lo = f2bf(acc[2 * i]);
    unsigned int hi = f2bf(acc[2 * i + 1]);
    p[i] = lo | (hi << 16);
  }
  *(uint4*)&out[(long)node * KP + o] = r;
}

// ---------------- mega weight transpose: all matrices in ONE launch ----------------
#define NWT 10
struct WtTab {
  const float* W[NWT];
  ushort_t* WT[NWT];
  int K[NWT], N[NWT], KP[NWT], Npad[NWT];
  int cumblk[NWT + 1];
};

__global__ __launch_bounds__(256) void wt_all_k(WtTab tab) {
  int b = blockIdx.x;
  int m = 0;
  while (b >= tab.cumblk[m + 1]) ++m;
  int i = (b - tab.cumblk[m]) * 256 + threadIdx.x;
  int KP = tab.KP[m];
  int tot = tab.Npad[m] * KP;
  if (i >= tot) return;
  int n = i / KP, k = i % KP;
  float v = (k < tab.K[m] && n < tab.N[m]) ? tab.W[m][(long)k * tab.N[m] + n] : 0.f;
  tab.WT[m][i] = f2bf(v);
}

// ---------------- register-direct bf16 MFMA conv GEMM (relu store, epilogue bias) ----------------
template <int KP>
__global__ __launch_bounds__(256) void conv_gemm2_k(
    const ushort_t* __restrict__ A, const ushort_t* __restrict__ WT,
    const float* __restrict__ bias, ushort_t* __restrict__ Cout, int M, int Nc,
    int OW, int NT) {
  constexpr int NKS = KP / 32;
  int tid = threadIdx.x;
  int wid = tid >> 6, lane = tid & 63;
  int lr = lane & 15, q = lane >> 4;
  int lk = q * 8;
  int row0 = blockIdx.x * 64;
  int arow = row0 + wid * 16 + lr;

  short8v a[NKS];
  const ushort_t* ap = A + (long)arow * KP + lk;
#pragma unroll
  for (int ks = 0; ks < NKS; ++ks) a[ks] = *(const short8v*)(ap + ks * 32);

  for (int ct = 0; ct < NT; ++ct) {
    int col0 = ct * 64;
    float4v acc[4];
#pragma unroll
    for (int i = 0; i < 4; ++i) acc[i] = (float4v){0.f, 0.f, 0.f, 0.f};
#pragma unroll
    for (int ks = 0; ks < NKS; ++ks) {
#pragma unroll
      for (int nf = 0; nf < 4; ++nf) {
        short8v b =
            *(const short8v*)&WT[(long)(col0 + nf * 16 + lr) * KP + ks * 32 + lk];
        acc[nf] = __builtin_amdgcn_mfma_f32_16x16x32_bf16(a[ks], b, acc[nf], 0, 0, 0);
      }
    }
#pragma unroll
    for (int nf = 0; nf < 4; ++nf) {
      int gc = col0 + nf * 16 + lr;
      if (gc >= OW) continue;
      float bv = (gc < Nc) ? bias[gc] : 0.f;
#pragma unroll
      for (int i = 0; i < 4; ++i) {
        int gr = row0 + wid * 16 + q * 4 + i;
        if (gr < M) {
          float v = (gc < Nc) ? fmaxf(acc[nf][i] + bv, 0.f) : 0.f;
          Cout[(long)gr * OW + gc] = f2bf(v);
        }
      }
    }
  }
}

// ---------------- per-(graph, 2 col-tiles) conv2 + pool: one wave, no LDS ----------------
template <int KP>
__global__ __launch_bounds__(64) void conv_pool2_k(
    const ushort_t* __restrict__ A, const ushort_t* __restrict__ WT,
    const float* __restrict__ bias, const int* __restrict__ gstart,
    float* __restrict__ pool, int Nc, int NCpool, int NT) {
  constexpr int NKS = KP / 32;
  int g = blockIdx.x;
  int ct0 = blockIdx.y * 2;
  int rs = gstart[g], re = gstart[g + 1];
  int rows = re - rs;
  int lane = threadIdx.x;
  int lr = lane & 15, q = lane >> 4, lk = q * 8;

  short8v bfr[2][NKS][4];
  float bv[2][4];
#pragma unroll
  for (int T = 0; T < 2; ++T) {
    int ct = min(ct0 + T, NT - 1);
    int col0 = ct * 64;
#pragma unroll
    for (int nf = 0; nf < 4; ++nf) {
      int gc = col0 + nf * 16 + lr;
      bv[T][nf] = (gc < Nc) ? bias[gc] : 0.f;
#pragma unroll
      for (int ks = 0; ks < NKS; ++ks)
        bfr[T][ks][nf] = *(const short8v*)&WT[(long)gc * KP + ks * 32 + lk];
    }
  }

  float wsums[2][4] = {}, wmaxs[2][4] = {};
  int nch = (rows + 15) >> 4;
  int rem = rows & 15;
  const ushort_t* ap = A + (long)(rs + lr) * KP + lk;

  short8v a0[NKS], a1[NKS];
  if (nch > 0) {
#pragma unroll
    for (int ks = 0; ks < NKS; ++ks) a0[ks] = *(const short8v*)(ap + ks * 32);
  }
  for (int c = 0; c < nch; ++c) {
    const ushort_t* apn = ap + (long)16 * KP;
    if (c + 1 < nch) {
#pragma unroll
      for (int ks = 0; ks < NKS; ++ks) a1[ks] = *(const short8v*)(apn + ks * 32);
    }
    bool tail = (c == nch - 1) && (rem != 0);
#pragma unroll
    for (int T = 0; T < 2; ++T) {
      float4v acc[4];
#pragma unroll
      for (int nf = 0; nf < 4; ++nf)
        acc[nf] = (float4v){bv[T][nf], bv[T][nf], bv[T][nf], bv[T][nf]};
#pragma unroll
      for (int ks = 0; ks < NKS; ++ks)
#pragma unroll
        for (int nf = 0; nf < 4; ++nf)
          acc[nf] = __builtin_amdgcn_mfma_f32_16x16x32_bf16(a0[ks], bfr[T][ks][nf],
                                                            acc[nf], 0, 0, 0);
      if (!tail) {
#pragma unroll
        for (int nf = 0; nf < 4; ++nf) {
          float r0 = fmaxf(acc[nf][0], 0.f), r1 = fmaxf(acc[nf][1], 0.f);
          float r2 = fmaxf(acc[nf][2], 0.f), r3 = fmaxf(acc[nf][3], 0.f);
          wsums[T][nf] += (r0 + r1) + (r2 + r3);
          wmaxs[T][nf] = fmaxf(wmaxs[T][nf], fmaxf(fmaxf(acc[nf][0], acc[nf][1]),
                                                   fmaxf(acc[nf][2], acc[nf][3])));
        }
      } else {
#pragma unroll
        for (int nf = 0; nf < 4; ++nf) {
          float v[4];
#pragma unroll
          for (int i = 0; i < 4; ++i)
            v[i] = ((q * 4 + i) < rem) ? fmaxf(acc[nf][i], 0.f) : 0.f;
          wsums[T][nf] += (v[0] + v[1]) + (v[2] + v[3]);
          wmaxs[T][nf] =
              fmaxf(wmaxs[T][nf], fmaxf(fmaxf(v[0], v[1]), fmaxf(v[2], v[3])));
        }
      }
    }
#pragma unroll
    for (int ks = 0; ks < NKS; ++ks) a0[ks] = a1[ks];
    ap = apn;
  }

  float inv = 1.f / fmaxf((float)rows, 1.f);
#pragma unroll
  for (int T = 0; T < 2; ++T) {
    int ct = ct0 + T;
    if (ct >= NT) continue;
#pragma unroll
    for (int nf = 0; nf < 4; ++nf) {
      float s = wsums[T][nf];
      float m = wmaxs[T][nf];
      s += __shfl_xor(s, 16);
      s += __shfl_xor(s, 32);
      m = fmaxf(m, __shfl_xor(m, 16));
      m = fmaxf(m, __shfl_xor(m, 32));
      int gc = ct * 64 + nf * 16 + lr;
      if (q == 0 && gc < Nc) {
        pool[(long)g * 2 * NCpool + gc] = s * inv;
        pool[(long)g * 2 * NCpool + NCpool + gc] = m;
      }
    }
  }
}

// ---------------- bf16 MFMA split-K FC GEMM (register-direct, simple form) ----------------
__global__ __launch_bounds__(256) void fc_mfma_k(const ushort_t* __restrict__ A,
                                                 const ushort_t* __restrict__ WT,
                                                 float* __restrict__ PART, int KP,
                                                 int Nc, int Kc) {
  int tid = threadIdx.x;
  int wid = tid >> 6, lane = tid & 63;
  int lr = lane & 15, q = lane >> 4, lk = q * 8;
  int row0 = blockIdx.y * 64, col0 = blockIdx.x * 64;
  int M = gridDim.y * 64;
  int kbeg = blockIdx.z * Kc;
  int arow = row0 + wid * 16 + lr;
  const ushort_t* ap = A + (long)arow * KP + kbeg + lk;
  const ushort_t* wp = WT + (long)col0 * KP + kbeg + lk;

  float4v acc[4];
#pragma unroll
  for (int i = 0; i < 4; ++i) acc[i] = (float4v){0.f, 0.f, 0.f, 0.f};

  for (int k0 = 0; k0 < Kc; k0 += 32) {
    short8v a = *(const short8v*)(ap + k0);
#pragma unroll
    for (int nf = 0; nf < 4; ++nf) {
      short8v b = *(const short8v*)(wp + (long)(nf * 16 + lr) * KP + k0);
      acc[nf] = __builtin_amdgcn_mfma_f32_16x16x32_bf16(a, b, acc[nf], 0, 0, 0);
    }
  }

  float* P = PART + (long)blockIdx.z * M * Nc;
#pragma unroll
  for (int nf = 0; nf < 4; ++nf) {
    int gc = col0 + nf * 16 + lr;
#pragma unroll
    for (int i = 0; i < 4; ++i) {
      int gr = row0 + wid * 16 + q * 4 + i;
      P[(long)gr * Nc + gc] = acc[nf][i];
    }
  }
}

// reduce partials + bias (+relu); writes f32 (Cf) and/or bf16 (Cb)
__global__ __launch_bounds__(256) void sk_epi2_k(const float* __restrict__ PART,
                                                 const float* __restrict__ bias,
                                                 float* __restrict__ Cf,
                                                 ushort_t* __restrict__ Cb, int M,
                                                 int Nc, int SK, int relu) {
  long idx = (long)blockIdx.x * 256 + threadIdx.x;
  if (idx >= (long)M * Nc) return;
  int c = (int)(idx % Nc);
  float s = bias[c];
  for (int z = 0; z < SK; ++z) s += PART[(long)z * M * Nc + idx];
  if (relu) s = fmaxf(s, 0.f);
  if (Cf) Cf[idx] = s;
  if (Cb) Cb[idx] = f2bf(s);
}

// ---------------- pairnorm stats ----------------
__global__ __launch_bounds__(256) void colstat_part_k(const float* __restrict__ X,
                                                      float* __restrict__ PS,
                                                      float* __restrict__ ssqtot,
                                                      int Rows, int Cols, int CR) {
  __shared__ float sred[256];
  int c0 = blockIdx.x * 64;
  int chunk = blockIdx.y;
  int t = threadIdx.x;
  int c = c0 + (t & 63);
  int rg = t >> 6;
  int rbeg = chunk * CR, rend = min(Rows, rbeg + CR);
  float s = 0.f, s2 = 0.f;
  if (c < Cols) {
    for (int r = rbeg + rg; r < rend; r += 4) {
      float v = X[(long)r * Cols + c];
      s += v;
      s2 += v * v;
    }
  }
  sred[t] = s;
  __syncthreads();
  if (t < 64 && c0 + t < Cols)
    PS[(long)chunk * Cols + c0 + t] = sred[t] + sred[t + 64] + sred[t + 128] + sred[t + 192];
  for (int off = 32; off > 0; off >>= 1) s2 += __shfl_down(s2, off);
  if ((t & 63) == 0) atomicAdd(ssqtot, s2);
}

// fused: cm finalize + pairnorm scale (single block)
__global__ __launch_bounds__(256) void colfin_scale_k(const float* __restrict__ PS,
                                                      float* __restrict__ cm,
                                                      const float* __restrict__ ssqtot,
                                                      float* __restrict__ scale,
                                                      int Rows, int Cols, int nchunk) {
  __shared__ float red[256];
  int t = threadIdx.x;
  float local = 0.f;
  for (int c = t; c < Cols; c += 256) {
    float s = 0.f;
    for (int z = 0; z < nchunk; ++z) s += PS[(long)z * Cols + c];
    float m = s / Rows;
    cm[c] = m;
    local += m * m;
  }
  red[t] = local;
  __syncthreads();
  for (int off = 128; off > 0; off >>= 1) {
    if (t < off) red[t] += red[t + off];
    __syncthreads();
  }
  if (t == 0) {
    float ssq = ssqtot[0] - (float)Rows * red[0];
    scale[0] = 1.f / sqrtf(1e-5f + ssq / Rows);
  }
}

__global__ __launch_bounds__(256) void pn_apply2_k(const float* __restrict__ X,
                                                   const float* __restrict__ cm,
                                                   const float* __restrict__ scale,
                                                   ushort_t* __restrict__ outB,
                                                   int Rows, int Cols, int KP1) {
  long idx = (long)blockIdx.x * 256 + threadIdx.x;
  if (idx >= (long)Rows * KP1) return;
  int r = (int)(idx / KP1), c = (int)(idx % KP1);
  float v = 0.f;
  if (c < Cols) v = (X[(long)r * Cols + c] - cm[c]) * scale[0];
  outB[idx] = f2bf(v);
}

// ---------------- batchnorm, two-stage ----------------
__global__ __launch_bounds__(256) void bn_part_k(const float* __restrict__ X,
                                                 float* __restrict__ PS,
                                                 float* __restrict__ PQ, int Rows,
                                                 int Cols, int CR) {
  __shared__ float s1[256], s2l[256];
  int c0 = blockIdx.x * 64;
  int chunk = blockIdx.y;
  int t = threadIdx.x;
  int c = c0 + (t & 63);
  int rg = t >> 6;
  int rbeg = chunk * CR, rend = min(Rows, rbeg + CR);
  float a = 0.f, b = 0.f;
  if (c < Cols) {
    for (int r = rbeg + rg; r < rend; r += 4) {
      float v = X[(long)r * Cols + c];
      a += v;
      b += v * v;
    }
  }
  s1[t] = a;
  s2l[t] = b;
  __syncthreads();
  if (t < 64 && c0 + t < Cols) {
    PS[(long)chunk * Cols + c0 + t] = s1[t] + s1[t + 64] + s1[t + 128] + s1[t + 192];
    PQ[(long)chunk * Cols + c0 + t] = s2l[t] + s2l[t + 64] + s2l[t + 128] + s2l[t + 192];
  }
}

__global__ __launch_bounds__(256) void bn_fin_k(const float* __restrict__ PS,
                                                const float* __restrict__ PQ,
                                                float* __restrict__ mu,
                                                float* __restrict__ var, int Rows,
                                                int Cols, int nchunk) {
  int c = blockIdx.x * 256 + threadIdx.x;
  if (c >= Cols) return;
  float s = 0.f, q = 0.f;
  for (int z = 0; z < nchunk; ++z) {
    s += PS[(long)z * Cols + c];
    q += PQ[(long)z * Cols + c];
  }
  float m = s / Rows;
  mu[c] = m;
  var[c] = q / Rows - m * m;
}

__global__ void bn_apply2_k(float* __restrict__ X, const float* __restrict__ mu,
                            const float* __restrict__ var, const float* __restrict__ g,
                            const float* __restrict__ b, ushort_t* __restrict__ XB16,
                            int Rows, int Cols) {
  long idx = (long)blockIdx.x * 256 + threadIdx.x;
  if (idx >= (long)Rows * Cols) return;
  int c = (int)(idx % Cols);
  float v = (X[idx] - mu[c]) / sqrtf(var[c] + 1e-5f) * g[c] + b[c];
  X[idx] = v;
  XB16[idx] = f2bf(v);
}

__global__ __launch_bounds__(64) void ff2_k(const ushort_t* __restrict__ Z,
                                            const float* __restrict__ W2,
                                            const float* __restrict__ b2,
                                            float* __restrict__ alpha,
                                            float* __restrict__ beta, int K) {
  int row = blockIdx.x;
  int t = threadIdx.x;
  float s0 = 0.f, s1 = 0.f;
  for (int k = t; k < K; k += 64) {
    float z = bf2f(Z[(long)row * K + k]);
    s0 += z * W2[2 * k];
    s1 += z * W2[2 * k + 1];
  }
  for (int off = 32; off > 0; off >>= 1) {
    s0 += __shfl_down(s0, off);
    s1 += __shfl_down(s1, off);
  }
  if (t == 0) {
    alpha[row] = 1.f / (1.f + expf(-(s0 + b2[0])));
    beta[row] = 1.f / (1.f + expf(-(s1 + b2[1])));
  }
}

// ---------------- branch driver (weights pre-transposed) ----------------
template <int KP>
static void run_branch(const float* x, const int* ei, const int* bat,
                       const float* bc1, const float* bc2, const float* fgb1,
                       const float* fgb2, const float* fgg, const float* fgbt,
                       const float* ffb1, const float* ffw2, const float* ffb2,
                       int N, int F, float* out_alpha, float* out_beta,
                       float* out_xg, ushort_t* XB, ushort_t* XA, ushort_t* H,
                       const ushort_t* WTc1, const ushort_t* WTc2,
                       const ushort_t* WTF1, const ushort_t* WTF2,
                       const ushort_t* WTFF, int* rowstart, int* BC, int* boff,
                       int* adj, int* GS, float* POOL, float* CM, float* MU,
                       float* VAR, float* SSQ, float* PSUM, float* PSQ,
                       ushort_t* POOLB, ushort_t* G1B, ushort_t* XGB,
                       ushort_t* Z1B, float* PART, hipStream_t stream) {
  const int NC = F * 10;
  const int Bn = NGRAPH;
  const int* src = ei;
  const int* dst = ei + EDGES;
  const int MB = (N + 63) / 64;
  const int Mpad = MB * 64;
  const int NB = (N + 255) >> 8;

  // branch-start zero (BC + XA pad + SSQ) in one launch
  long npad = (long)(Mpad - N) * KP;
  long zmax = max((long)(2 * NBMAX), npad);
  bzero_k<<<(int)((zmax + 255) / 256), 256, 0, stream>>>(BC, 2 * NBMAX,
                                                         XA + (size_t)N * KP, npad, SSQ);

  // CSR build (EB aliases XB which is rewritten later)
  int2* EB = (int2*)XB;
  int* bcnt = BC;
  int* bcur = BC + NBMAX;
  bcount_k<<<(EDGES + 4095) / 4096, 256, 0, stream>>>(dst, bcnt, EDGES, NB);
  scan_gstart_k<<<1 + (NGRAPH + 512) / 512, 512, 0, stream>>>(bcnt, boff, NB, bat,
                                                              GS, N, NGRAPH);
  bscatter_k<<<(EDGES + 4095) / 4096, 256, 0, stream>>>(src, dst, boff, bcur, EB, EDGES, NB);
  bucket_csr_k<<<NB, 256, 0, stream>>>(EB, boff, rowstart, adj, N, NB, EDGES);

  constexpr int CH = KP / 8;
  tobf16_k<KP><<<(int)(((long)N * KP + 255) / 256), 256, 0, stream>>>(x, XB, N, F);
  // conv1
  gather_k<KP><<<(int)(((long)N * CH + 255) / 256), 256, 0, stream>>>(XB, rowstart, adj, XA, N);
  conv_gemm2_k<KP><<<MB, 256, 0, stream>>>(XA, WTc1, bc1, H, N, F, KP, (KP + 63) / 64);
  // conv2 + per-(graph, 2-tile) pool
  gather_k<KP><<<(int)(((long)N * CH + 255) / 256), 256, 0, stream>>>(H, rowstart, adj, XA, N);
  int Npad2 = ((NC + 63) / 64) * 64;
  int NT2 = Npad2 / 64;
  conv_pool2_k<KP><<<dim3(NGRAPH, (NT2 + 1) / 2), 64, 0, stream>>>(XA, WTc2, bc2, GS,
                                                                   POOL, NC, NC, NT2);

  // pairnorm stats (two-stage; fin+scale fused)
  int Cols = 2 * NC;
  const int NCH = 16, CR = NGRAPH / NCH;
  colstat_part_k<<<dim3((Cols + 63) / 64, NCH), 256, 0, stream>>>(POOL, PSUM, SSQ, Bn, Cols, CR);
  colfin_scale_k<<<1, 256, 0, stream>>>(PSUM, CM, SSQ, SSQ + 1, Bn, Cols, NCH);

  // ---- FC stack: bf16 MFMA split-K ----
  int KP1 = ((Cols + 127) / 128) * 128;
  pn_apply2_k<<<(int)(((long)Bn * KP1 + 255) / 256), 256, 0, stream>>>(
      POOL, CM, SSQ + 1, POOLB, Bn, Cols, KP1);
  fc_mfma_k<<<dim3(16, 16, 4), 256, 0, stream>>>(POOLB, WTF1, PART, KP1, 1024, KP1 / 4);
  sk_epi2_k<<<(Bn * 1024 + 255) / 256, 256, 0, stream>>>(PART, fgb1, nullptr, G1B, Bn, 1024, 4, 1);
  fc_mfma_k<<<dim3(8, 16, 4), 256, 0, stream>>>(G1B, WTF2, PART, 1024, 512, 256);
  sk_epi2_k<<<(Bn * 512 + 255) / 256, 256, 0, stream>>>(PART, fgb2, out_xg, nullptr, Bn, 512, 4, 0);
  bn_part_k<<<dim3(8, 8), 256, 0, stream>>>(out_xg, PSUM, PSQ, Bn, 512, 128);
  bn_fin_k<<<2, 256, 0, stream>>>(PSUM, PSQ, MU, VAR, Bn, 512, 8);
  bn_apply2_k<<<(Bn * 512 + 255) / 256, 256, 0, stream>>>(out_xg, MU, VAR, fgg, fgbt, XGB, Bn, 512);
  fc_mfma_k<<<dim3(4, 16, 8), 256, 0, stream>>>(XGB, WTFF, PART, 512, 256, 64);
  sk_epi2_k<<<(Bn * 256 + 255) / 256, 256, 0, stream>>>(PART, ffb1, nullptr, Z1B, Bn, 256, 8, 1);
  ff2_k<<<Bn, 64, 0, stream>>>(Z1B, ffw2, ffb2, out_alpha, out_beta, 256);
}

extern "C" void kernel_launch(void* const* d_in, const int* in_sizes, int n_in,
                              void* d_out, int out_size, void* d_ws, size_t ws_size,
                              hipStream_t stream) {
  if (n_in < 34) return;
  const float* x0 = (const float*)d_in[0];
  const int* ei0 = (const int*)d_in[1];
  const int* b0 = (const int*)d_in[2];
  const float* x1 = (const float*)d_in[3];
  const int* ei1 = (const int*)d_in[4];
  const int* b1 = (const int*)d_in[5];
  const float* w_c1 = (const float*)d_in[6];
  const float* b_c1 = (const float*)d_in[7];
  const float* w_c2 = (const float*)d_in[8];
  const float* b_c2 = (const float*)d_in[9];
  const float* w_c3 = (const float*)d_in[10];
  const float* b_c3 = (const float*)d_in[11];
  const float* w_c4 = (const float*)d_in[12];
  const float* b_c4 = (const float*)d_in[13];
  const float* fg0_w1 = (const float*)d_in[14];
  const float* fg0_b1 = (const float*)d_in[15];
  const float* fg0_w2 = (const float*)d_in[16];
  const float* fg0_b2 = (const float*)d_in[17];
  const float* fg0_g = (const float*)d_in[18];
  const float* fg0_bt = (const float*)d_in[19];
  const float* fg1_w1 = (const float*)d_in[20];
  const float* fg1_b1 = (const float*)d_in[21];
  const float* fg1_w2 = (const float*)d_in[22];
  const float* fg1_b2 = (const float*)d_in[23];
  const float* fg1_g = (const float*)d_in[24];
  const float* fg1_bt = (const float*)d_in[25];
  const float* ff0_w1 = (const float*)d_in[26];
  const float* ff0_b1 = (const float*)d_in[27];
  const float* ff0_w2 = (const float*)d_in[28];
  const float* ff0_b2 = (const float*)d_in[29];
  const float* ff1_w1 = (const float*)d_in[30];
  const float* ff1_b1 = (const float*)d_in[31];
  const float* ff1_w2 = (const float*)d_in[32];
  const float* ff1_b2 = (const float*)d_in[33];

  float* out = (float*)d_out;
  float* alpha = out;
  float* beta = out + 1024;
  float* xg0 = out + 2048;
  float* xg1 = out + 2048 + 1024 * 512;
  float* alpha1 = out + 2048 + 2 * 1024 * 512;
  float* beta1 = alpha1 + 1024;

  char* w = (char*)d_ws;
  auto alloc = [&](size_t bytes) -> void* {
    void* p = (void*)w;
    w += ((bytes + 255) / 256) * 256;
    return p;
  };
  const int Mpad = ((NNODES + 63) / 64) * 64;
  ushort_t* XB = (ushort_t*)alloc((size_t)Mpad * 96 * 2);
  ushort_t* XA = (ushort_t*)alloc((size_t)Mpad * 96 * 2);
  ushort_t* H = (ushort_t*)alloc((size_t)Mpad * 96 * 2);
  int* rowstart = (int*)alloc((size_t)(NNODES + 1) * 4);
  int* BC = (int*)alloc(2 * NBMAX * 4);
  int* boff = (int*)alloc((NBMAX + 1) * 4);
  int* adj = (int*)alloc((size_t)EDGES * 4);
  int* GS = (int*)alloc((size_t)(NGRAPH + 1) * 4);
  float* POOL = (float*)alloc((size_t)NGRAPH * 1860 * 4);
  float* CM = (float*)alloc(1860 * 4);
  float* MU = (float*)alloc(512 * 4);
  float* VAR = (float*)alloc(512 * 4);
  float* SSQ = (float*)alloc(256);
  float* PSUM = (float*)alloc((size_t)16 * 1920 * 4);
  float* PSQ = (float*)alloc((size_t)8 * 512 * 4);
  ushort_t* POOLB = (ushort_t*)alloc((size_t)NGRAPH * 1920 * 2);
  ushort_t* G1B = (ushort_t*)alloc((size_t)NGRAPH * 1024 * 2);
  ushort_t* XGB = (ushort_t*)alloc((size_t)NGRAPH * 512 * 2);
  ushort_t* Z1B = (ushort_t*)alloc((size_t)NGRAPH * 256 * 2);
  // per-branch pre-transposed weights
  ushort_t* WTc1_0 = (ushort_t*)alloc((size_t)128 * 96 * 2);
  ushort_t* WTc2_0 = (ushort_t*)alloc((size_t)960 * 96 * 2);
  ushort_t* WTF1_0 = (ushort_t*)alloc((size_t)1024 * 1920 * 2);
  ushort_t* WTF2_0 = (ushort_t*)alloc((size_t)512 * 1024 * 2);
  ushort_t* WTFF_0 = (ushort_t*)alloc((size_t)256 * 512 * 2);
  ushort_t* WTc1_1 = (ushort_t*)alloc((size_t)64 * 64 * 2);
  ushort_t* WTc2_1 = (ushort_t*)alloc((size_t)448 * 64 * 2);
  ushort_t* WTF1_1 = (ushort_t*)alloc((size_t)1024 * 896 * 2);
  ushort_t* WTF2_1 = (ushort_t*)alloc((size_t)512 * 1024 * 2);
  ushort_t* WTFF_1 = (ushort_t*)alloc((size_t)256 * 512 * 2);
  if ((size_t)(w - (char*)d_ws) > ws_size) return;

  float* PART = (float*)XB;  // aliases XB (dead during FC phase)

  // ---- one mega transpose launch for all 10 weight matrices ----
  WtTab tab;
  auto setw = [&](int m, const float* W, ushort_t* WT, int K, int N, int KP, int Npad) {
    tab.W[m] = W;
    tab.WT[m] = WT;
    tab.K[m] = K;
    tab.N[m] = N;
    tab.KP[m] = KP;
    tab.Npad[m] = Npad;
  };
  setw(0, w_c1, WTc1_0, 93, 93, 96, 128);
  setw(1, w_c2, WTc2_0, 93, 930, 96, 960);
  setw(2, fg0_w1, WTF1_0, 1860, 1024, 1920, 1024);
  setw(3, fg0_w2, WTF2_0, 1024, 512, 1024, 512);
  setw(4, ff0_w1, WTFF_0, 512, 256, 512, 256);
  setw(5, w_c3, WTc1_1, 43, 43, 64, 64);
  setw(6, w_c4, WTc2_1, 43, 430, 64, 448);
  setw(7, fg1_w1, WTF1_1, 860, 1024, 896, 1024);
  setw(8, fg1_w2, WTF2_1, 1024, 512, 1024, 512);
  setw(9, ff1_w1, WTFF_1, 512, 256, 512, 256);
  tab.cumblk[0] = 0;
  for (int m = 0; m < NWT; ++m)
    tab.cumblk[m + 1] = tab.cumblk[m] + (tab.Npad[m] * tab.KP[m] + 255) / 256;
  wt_all_k<<<tab.cumblk[NWT], 256, 0, stream>>>(tab);

  run_branch<96>(x0, ei0, b0, b_c1, b_c2, fg0_b1, fg0_b2, fg0_g, fg0_bt, ff0_b1,
                 ff0_w2, ff0_b2, NNODES, 93, alpha, beta, xg0, XB, XA, H, WTc1_0,
                 WTc2_0, WTF1_0, WTF2_0, WTFF_0, rowstart, BC, boff, adj, GS, POOL,
                 CM, MU, VAR, SSQ, PSUM, PSQ, POOLB, G1B, XGB, Z1B, PART, stream);
  run_branch<64>(x1, ei1, b1, b_c3, b_c4, fg1_b1, fg1_b2, fg1_g, fg1_bt, ff1_b1,
                 ff1_w2, ff1_b2, NNODES, 43, alpha1, beta1, xg1, XB, XA, H, WTc1_1,
                 WTc2_1, WTF1_1, WTF2_1, WTFF_1, rowstart, BC, boff, adj, GS, POOL,
                 CM, MU, VAR, SSQ, PSUM, PSQ, POOLB, G1B, XGB, Z1B, PART, stream);
}

// Round 19
// 593.436 us; speedup vs baseline: 1.0130x; 1.0130x over previous
//
#include <hip/hip_runtime.h>
#include <hip/hip_bf16.h>
#include <math.h>

#define EDGES 800000
#define NNODES 100000
#define NGRAPH 1024

typedef __attribute__((ext_vector_type(8))) short short8v;
typedef __attribute__((ext_vector_type(4))) float float4v;
typedef unsigned short ushort_t;

__device__ inline ushort_t f2bf(float f) {
  __hip_bfloat16 h = __float2bfloat16(f);
  return *reinterpret_cast<ushort_t*>(&h);
}
__device__ inline float bf2f(ushort_t u) {
  return __uint_as_float(((unsigned int)u) << 16);
}

// ---------------- CSR build (bucketed, LDS-local) ----------------
#define NBMAX 512

__global__ __launch_bounds__(256) void bcount_k(const int* __restrict__ dst,
                                                int* __restrict__ bcnt, int E,
                                                int NB) {
  __shared__ int hist[NBMAX];
  int t = threadIdx.x;
  for (int b = t; b < NB; b += 256) hist[b] = 0;
  __syncthreads();
  int e0 = blockIdx.x * 4096;
  int e1 = min(E, e0 + 4096);
  for (int e = e0 + t; e < e1; e += 256) atomicAdd(&hist[dst[e] >> 8], 1);
  __syncthreads();
  for (int b = t; b < NB; b += 256)
    if (hist[b] > 0) atomicAdd(&bcnt[b], hist[b]);
}

__global__ __launch_bounds__(512) void bscan_k(const int* __restrict__ bcnt,
                                               int* __restrict__ boff, int NB) {
  __shared__ int tmp[512];
  int t = threadIdx.x;
  int v = (t < NB) ? bcnt[t] : 0;
  tmp[t] = v;
  __syncthreads();
  for (int off = 1; off < 512; off <<= 1) {
    int x = (t >= off) ? tmp[t - off] : 0;
    __syncthreads();
    tmp[t] += x;
    __syncthreads();
  }
  if (t < NB) boff[t] = tmp[t] - v;
  if (t == NB - 1) boff[NB] = tmp[t];
}

__global__ __launch_bounds__(256) void bscatter_k(const int* __restrict__ src,
                                                  const int* __restrict__ dst,
                                                  const int* __restrict__ boff,
                                                  int* __restrict__ bcur,
                                                  int2* __restrict__ EB, int E,
                                                  int NB) {
  __shared__ int hist[NBMAX], run[NBMAX], lcur[NBMAX];
  int t = threadIdx.x;
  for (int b = t; b < NB; b += 256) {
    hist[b] = 0;
    lcur[b] = 0;
  }
  __syncthreads();
  int e0 = blockIdx.x * 4096;
  int e1 = min(E, e0 + 4096);
  for (int e = e0 + t; e < e1; e += 256) atomicAdd(&hist[dst[e] >> 8], 1);
  __syncthreads();
  for (int b = t; b < NB; b += 256)
    if (hist[b] > 0) run[b] = atomicAdd(&bcur[b], hist[b]);
  __syncthreads();
  for (int e = e0 + t; e < e1; e += 256) {
    int d = dst[e];
    int b = d >> 8;
    int l = atomicAdd(&lcur[b], 1);
    int pos = boff[b] + run[b] + l;
    EB[pos] = make_int2(src[e], d);
  }
}

__global__ __launch_bounds__(256) void bucket_csr_k(const int2* __restrict__ EB,
                                                    const int* __restrict__ boff,
                                                    int* __restrict__ rowstart,
                                                    int* __restrict__ adj, int N,
                                                    int NB, int E) {
  __shared__ int cnt[256], pfx[256], lcur[256];
  int b = blockIdx.x, t = threadIdx.x;
  int e0 = boff[b], e1 = boff[b + 1];
  cnt[t] = 0;
  __syncthreads();
  for (int e = e0 + t; e < e1; e += 256) atomicAdd(&cnt[EB[e].y & 255], 1);
  __syncthreads();
  int v = cnt[t];
  pfx[t] = v;
  __syncthreads();
  for (int off = 1; off < 256; off <<= 1) {
    int x = (t >= off) ? pfx[t - off] : 0;
    __syncthreads();
    pfx[t] += x;
    __syncthreads();
  }
  int node = (b << 8) + t;
  if (node < N) rowstart[node] = e0 + pfx[t] - v;
  if (b == NB - 1 && t == 0) rowstart[N] = E;
  lcur[t] = 0;
  __syncthreads();
  for (int e = e0 + t; e < e1; e += 256) {
    int2 ed = EB[e];
    int ln = ed.y & 255;
    int l = atomicAdd(&lcur[ln], 1);
    adj[e0 + pfx[ln] - cnt[ln] + l] = ed.x;
  }
}

// ---------------- graph start offsets (batch sorted) ----------------
__global__ __launch_bounds__(256) void gstart_k(const int* __restrict__ bat,
                                                int* __restrict__ gs, int N, int B) {
  int g = blockIdx.x * 256 + threadIdx.x;
  if (g > B) return;
  if (g == B) {
    gs[B] = N;
    return;
  }
  int lo = 0, hi = N;
  while (lo < hi) {
    int mid = (lo + hi) >> 1;
    if (bat[mid] < g) lo = mid + 1;
    else hi = mid;
  }
  gs[g] = lo;
}

// ---------------- f32 -> padded bf16 ----------------
template <int KP>
__global__ __launch_bounds__(256) void tobf16_k(const float* __restrict__ x,
                                                ushort_t* __restrict__ out, int M,
                                                int F) {
  long i = (long)blockIdx.x * 256 + threadIdx.x;
  if (i >= (long)M * KP) return;
  int r = (int)(i / KP), c = (int)(i % KP);
  float v = (c < F) ? x[(long)r * F + c] : 0.f;
  out[i] = f2bf(v);
}

// ---------------- gather: out[i] = X[i] + sum_{j in nbr(i)} X[j]  (bf16) ----------------
template <int KP>
__global__ __launch_bounds__(256) void gather_k(const ushort_t* __restrict__ X,
                                                const int* __restrict__ rowstart,
                                                const int* __restrict__ adj,
                                                ushort_t* __restrict__ out, int M) {
  constexpr int CH = KP / 8;
  long tid = (long)blockIdx.x * 256 + threadIdx.x;
  if (tid >= (long)M * CH) return;
  int node = (int)(tid / CH), ch = (int)(tid % CH);
  int o = ch * 8;
  float acc[8];
  uint4 self = *(const uint4*)&X[(long)node * KP + o];
  {
    const unsigned int u[4] = {self.x, self.y, self.z, self.w};
#pragma unroll
    for (int i = 0; i < 4; ++i) {
      acc[2 * i] = __uint_as_float((u[i] & 0xFFFFu) << 16);
      acc[2 * i + 1] = __uint_as_float(u[i] & 0xFFFF0000u);
    }
  }
  auto add4 = [&](uint4 v) {
    const unsigned int u[4] = {v.x, v.y, v.z, v.w};
#pragma unroll
    for (int i = 0; i < 4; ++i) {
      acc[2 * i] += __uint_as_float((u[i] & 0xFFFFu) << 16);
      acc[2 * i + 1] += __uint_as_float(u[i] & 0xFFFF0000u);
    }
  };
  int rs = rowstart[node], re = rowstart[node + 1];
  int e = rs;
  for (; e + 4 <= re; e += 4) {
    int j0 = adj[e], j1 = adj[e + 1], j2 = adj[e + 2], j3 = adj[e + 3];
    uint4 v0 = *(const uint4*)&X[(long)j0 * KP + o];
    uint4 v1 = *(const uint4*)&X[(long)j1 * KP + o];
    uint4 v2 = *(const uint4*)&X[(long)j2 * KP + o];
    uint4 v3 = *(const uint4*)&X[(long)j3 * KP + o];
    add4(v0);
    add4(v1);
    add4(v2);
    add4(v3);
  }
  for (; e < re; ++e) {
    int j = adj[e];
    add4(*(const uint4*)&X[(long)j * KP + o]);
  }
  uint4 r;
  unsigned int* p = &r.x;
#pragma unroll
  for (int i = 0; i < 4; ++i) {
    unsigned int lo = f2bf(acc[2 * i]);
    unsigned int hi = f2bf(acc[2 * i + 1]);
    p[i] = lo | (hi << 16);
  }
  *(uint4*)&out[(long)node * KP + o] = r;
}

// ---------------- weight transpose + bf16: WT[n][k] = W[k][n] ----------------
// strided single-pass form (LDS-tiled variant regressed twice; W is L2-resident).
__global__ __launch_bounds__(256) void wt_k(const float* __restrict__ W,
                                            ushort_t* __restrict__ WT, int K, int N,
                                            int KP, int Npad) {
  int i = blockIdx.x * 256 + threadIdx.x;
  if (i >= Npad * KP) return;
  int n = i / KP, k = i % KP;
  float v = (k < K && n < N) ? W[(long)k * N + n] : 0.f;
  WT[i] = f2bf(v);
}

// ---------------- register-direct bf16 MFMA conv GEMM (relu store, epilogue bias) ----------------
template <int KP>
__global__ __launch_bounds__(256) void conv_gemm2_k(
    const ushort_t* __restrict__ A, const ushort_t* __restrict__ WT,
    const float* __restrict__ bias, ushort_t* __restrict__ Cout, int M, int Nc,
    int OW, int NT) {
  constexpr int NKS = KP / 32;
  int tid = threadIdx.x;
  int wid = tid >> 6, lane = tid & 63;
  int lr = lane & 15, q = lane >> 4;
  int lk = q * 8;
  int row0 = blockIdx.x * 64;
  int arow = row0 + wid * 16 + lr;

  short8v a[NKS];
  const ushort_t* ap = A + (long)arow * KP + lk;
#pragma unroll
  for (int ks = 0; ks < NKS; ++ks) a[ks] = *(const short8v*)(ap + ks * 32);

  for (int ct = 0; ct < NT; ++ct) {
    int col0 = ct * 64;
    float4v acc[4];
#pragma unroll
    for (int i = 0; i < 4; ++i) acc[i] = (float4v){0.f, 0.f, 0.f, 0.f};
#pragma unroll
    for (int ks = 0; ks < NKS; ++ks) {
#pragma unroll
      for (int nf = 0; nf < 4; ++nf) {
        short8v b =
            *(const short8v*)&WT[(long)(col0 + nf * 16 + lr) * KP + ks * 32 + lk];
        acc[nf] = __builtin_amdgcn_mfma_f32_16x16x32_bf16(a[ks], b, acc[nf], 0, 0, 0);
      }
    }
#pragma unroll
    for (int nf = 0; nf < 4; ++nf) {
      int gc = col0 + nf * 16 + lr;
      if (gc >= OW) continue;
      float bv = (gc < Nc) ? bias[gc] : 0.f;
#pragma unroll
      for (int i = 0; i < 4; ++i) {
        int gr = row0 + wid * 16 + q * 4 + i;
        if (gr < M) {
          float v = (gc < Nc) ? fmaxf(acc[nf][i] + bv, 0.f) : 0.f;
          Cout[(long)gr * OW + gc] = f2bf(v);
        }
      }
    }
  }
}

// ---------------- per-(graph, 2 col-tiles) conv2 + pool: one wave, no LDS ----------------
template <int KP>
__global__ __launch_bounds__(64) void conv_pool2_k(
    const ushort_t* __restrict__ A, const ushort_t* __restrict__ WT,
    const float* __restrict__ bias, const int* __restrict__ gstart,
    float* __restrict__ pool, int Nc, int NCpool, int NT) {
  constexpr int NKS = KP / 32;
  int g = blockIdx.x;
  int ct0 = blockIdx.y * 2;
  int rs = gstart[g], re = gstart[g + 1];
  int rows = re - rs;
  int lane = threadIdx.x;
  int lr = lane & 15, q = lane >> 4, lk = q * 8;

  short8v bfr[2][NKS][4];
  float bv[2][4];
#pragma unroll
  for (int T = 0; T < 2; ++T) {
    int ct = min(ct0 + T, NT - 1);
    int col0 = ct * 64;
#pragma unroll
    for (int nf = 0; nf < 4; ++nf) {
      int gc = col0 + nf * 16 + lr;
      bv[T][nf] = (gc < Nc) ? bias[gc] : 0.f;
#pragma unroll
      for (int ks = 0; ks < NKS; ++ks)
        bfr[T][ks][nf] = *(const short8v*)&WT[(long)gc * KP + ks * 32 + lk];
    }
  }

  float wsums[2][4] = {}, wmaxs[2][4] = {};
  int nch = (rows + 15) >> 4;
  int rem = rows & 15;
  const ushort_t* ap = A + (long)(rs + lr) * KP + lk;

  short8v a0[NKS], a1[NKS];
  if (nch > 0) {
#pragma unroll
    for (int ks = 0; ks < NKS; ++ks) a0[ks] = *(const short8v*)(ap + ks * 32);
  }
  for (int c = 0; c < nch; ++c) {
    const ushort_t* apn = ap + (long)16 * KP;
    if (c + 1 < nch) {
#pragma unroll
      for (int ks = 0; ks < NKS; ++ks) a1[ks] = *(const short8v*)(apn + ks * 32);
    }
    bool tail = (c == nch - 1) && (rem != 0);
#pragma unroll
    for (int T = 0; T < 2; ++T) {
      float4v acc[4];
#pragma unroll
      for (int nf = 0; nf < 4; ++nf)
        acc[nf] = (float4v){bv[T][nf], bv[T][nf], bv[T][nf], bv[T][nf]};
#pragma unroll
      for (int ks = 0; ks < NKS; ++ks)
#pragma unroll
        for (int nf = 0; nf < 4; ++nf)
          acc[nf] = __builtin_amdgcn_mfma_f32_16x16x32_bf16(a0[ks], bfr[T][ks][nf],
                                                            acc[nf], 0, 0, 0);
      if (!tail) {
#pragma unroll
        for (int nf = 0; nf < 4; ++nf) {
          float r0 = fmaxf(acc[nf][0], 0.f), r1 = fmaxf(acc[nf][1], 0.f);
          float r2 = fmaxf(acc[nf][2], 0.f), r3 = fmaxf(acc[nf][3], 0.f);
          wsums[T][nf] += (r0 + r1) + (r2 + r3);
          wmaxs[T][nf] = fmaxf(wmaxs[T][nf], fmaxf(fmaxf(acc[nf][0], acc[nf][1]),
                                                   fmaxf(acc[nf][2], acc[nf][3])));
        }
      } else {
#pragma unroll
        for (int nf = 0; nf < 4; ++nf) {
          float v[4];
#pragma unroll
          for (int i = 0; i < 4; ++i)
            v[i] = ((q * 4 + i) < rem) ? fmaxf(acc[nf][i], 0.f) : 0.f;
          wsums[T][nf] += (v[0] + v[1]) + (v[2] + v[3]);
          wmaxs[T][nf] =
              fmaxf(wmaxs[T][nf], fmaxf(fmaxf(v[0], v[1]), fmaxf(v[2], v[3])));
        }
      }
    }
#pragma unroll
    for (int ks = 0; ks < NKS; ++ks) a0[ks] = a1[ks];
    ap = apn;
  }

  float inv = 1.f / fmaxf((float)rows, 1.f);
#pragma unroll
  for (int T = 0; T < 2; ++T) {
    int ct = ct0 + T;
    if (ct >= NT) continue;
#pragma unroll
    for (int nf = 0; nf < 4; ++nf) {
      float s = wsums[T][nf];
      float m = wmaxs[T][nf];
      s += __shfl_xor(s, 16);
      s += __shfl_xor(s, 32);
      m = fmaxf(m, __shfl_xor(m, 16));
      m = fmaxf(m, __shfl_xor(m, 32));
      int gc = ct * 64 + nf * 16 + lr;
      if (q == 0 && gc < Nc) {
        pool[(long)g * 2 * NCpool + gc] = s * inv;
        pool[(long)g * 2 * NCpool + NCpool + gc] = m;
      }
    }
  }
}

// ---------------- bf16 MFMA split-K FC GEMM (register-direct, simple form) ----------------
__global__ __launch_bounds__(256) void fc_mfma_k(const ushort_t* __restrict__ A,
                                                 const ushort_t* __restrict__ WT,
                                                 float* __restrict__ PART, int KP,
                                                 int Nc, int Kc) {
  int tid = threadIdx.x;
  int wid = tid >> 6, lane = tid & 63;
  int lr = lane & 15, q = lane >> 4, lk = q * 8;
  int row0 = blockIdx.y * 64, col0 = blockIdx.x * 64;
  int M = gridDim.y * 64;
  int kbeg = blockIdx.z * Kc;
  int arow = row0 + wid * 16 + lr;
  const ushort_t* ap = A + (long)arow * KP + kbeg + lk;
  const ushort_t* wp = WT + (long)col0 * KP + kbeg + lk;

  float4v acc[4];
#pragma unroll
  for (int i = 0; i < 4; ++i) acc[i] = (float4v){0.f, 0.f, 0.f, 0.f};

  for (int k0 = 0; k0 < Kc; k0 += 32) {
    short8v a = *(const short8v*)(ap + k0);
#pragma unroll
    for (int nf = 0; nf < 4; ++nf) {
      short8v b = *(const short8v*)(wp + (long)(nf * 16 + lr) * KP + k0);
      acc[nf] = __builtin_amdgcn_mfma_f32_16x16x32_bf16(a, b, acc[nf], 0, 0, 0);
    }
  }

  float* P = PART + (long)blockIdx.z * M * Nc;
#pragma unroll
  for (int nf = 0; nf < 4; ++nf) {
    int gc = col0 + nf * 16 + lr;
#pragma unroll
    for (int i = 0; i < 4; ++i) {
      int gr = row0 + wid * 16 + q * 4 + i;
      P[(long)gr * Nc + gc] = acc[nf][i];
    }
  }
}

// reduce partials + bias (+relu); writes f32 (Cf) and/or bf16 (Cb)
__global__ __launch_bounds__(256) void sk_epi2_k(const float* __restrict__ PART,
                                                 const float* __restrict__ bias,
                                                 float* __restrict__ Cf,
                                                 ushort_t* __restrict__ Cb, int M,
                                                 int Nc, int SK, int relu) {
  long idx = (long)blockIdx.x * 256 + threadIdx.x;
  if (idx >= (long)M * Nc) return;
  int c = (int)(idx % Nc);
  float s = bias[c];
  for (int z = 0; z < SK; ++z) s += PART[(long)z * M * Nc + idx];
  if (relu) s = fmaxf(s, 0.f);
  if (Cf) Cf[idx] = s;
  if (Cb) Cb[idx] = f2bf(s);
}

// ---------------- pairnorm stats, two-stage ----------------
__global__ __launch_bounds__(256) void colstat_part_k(const float* __restrict__ X,
                                                      float* __restrict__ PS,
                                                      float* __restrict__ ssqtot,
                                                      int Rows, int Cols, int CR) {
  __shared__ float sred[256];
  int c0 = blockIdx.x * 64;
  int chunk = blockIdx.y;
  int t = threadIdx.x;
  int c = c0 + (t & 63);
  int rg = t >> 6;
  int rbeg = chunk * CR, rend = min(Rows, rbeg + CR);
  float s = 0.f, s2 = 0.f;
  if (c < Cols) {
    for (int r = rbeg + rg; r < rend; r += 4) {
      float v = X[(long)r * Cols + c];
      s += v;
      s2 += v * v;
    }
  }
  sred[t] = s;
  __syncthreads();
  if (t < 64 && c0 + t < Cols)
    PS[(long)chunk * Cols + c0 + t] = sred[t] + sred[t + 64] + sred[t + 128] + sred[t + 192];
  for (int off = 32; off > 0; off >>= 1) s2 += __shfl_down(s2, off);
  if ((t & 63) == 0) atomicAdd(ssqtot, s2);
}

__global__ __launch_bounds__(256) void colstat_fin_k(const float* __restrict__ PS,
                                                     float* __restrict__ cm, int Rows,
                                                     int Cols, int nchunk) {
  int c = blockIdx.x * 256 + threadIdx.x;
  if (c >= Cols) return;
  float s = 0.f;
  for (int z = 0; z < nchunk; ++z) s += PS[(long)z * Cols + c];
  cm[c] = s / Rows;
}

__global__ __launch_bounds__(256) void pn_scale_k(const float* __restrict__ cm,
                                                  const float* __restrict__ ssqtot,
                                                  float* __restrict__ scale, int Rows,
                                                  int Cols) {
  __shared__ float red[256];
  int t = threadIdx.x;
  float s = 0.f;
  for (int i = t; i < Cols; i += 256) {
    float v = cm[i];
    s += v * v;
  }
  red[t] = s;
  __syncthreads();
  for (int off = 128; off > 0; off >>= 1) {
    if (t < off) red[t] += red[t + off];
    __syncthreads();
  }
  if (t == 0) {
    float ssq = ssqtot[0] - (float)Rows * red[0];
    scale[0] = 1.f / sqrtf(1e-5f + ssq / Rows);
  }
}

__global__ __launch_bounds__(256) void pn_apply2_k(const float* __restrict__ X,
                                                   const float* __restrict__ cm,
                                                   const float* __restrict__ scale,
                                                   ushort_t* __restrict__ outB,
                                                   int Rows, int Cols, int KP1) {
  long idx = (long)blockIdx.x * 256 + threadIdx.x;
  if (idx >= (long)Rows * KP1) return;
  int r = (int)(idx / KP1), c = (int)(idx % KP1);
  float v = 0.f;
  if (c < Cols) v = (X[(long)r * Cols + c] - cm[c]) * scale[0];
  outB[idx] = f2bf(v);
}

// ---------------- batchnorm, two-stage ----------------
__global__ __launch_bounds__(256) void bn_part_k(const float* __restrict__ X,
                                                 float* __restrict__ PS,
                                                 float* __restrict__ PQ, int Rows,
                                                 int Cols, int CR) {
  __shared__ float s1[256], s2l[256];
  int c0 = blockIdx.x * 64;
  int chunk = blockIdx.y;
  int t = threadIdx.x;
  int c = c0 + (t & 63);
  int rg = t >> 6;
  int rbeg = chunk * CR, rend = min(Rows, rbeg + CR);
  float a = 0.f, b = 0.f;
  if (c < Cols) {
    for (int r = rbeg + rg; r < rend; r += 4) {
      float v = X[(long)r * Cols + c];
      a += v;
      b += v * v;
    }
  }
  s1[t] = a;
  s2l[t] = b;
  __syncthreads();
  if (t < 64 && c0 + t < Cols) {
    PS[(long)chunk * Cols + c0 + t] = s1[t] + s1[t + 64] + s1[t + 128] + s1[t + 192];
    PQ[(long)chunk * Cols + c0 + t] = s2l[t] + s2l[t + 64] + s2l[t + 128] + s2l[t + 192];
  }
}

__global__ __launch_bounds__(256) void bn_fin_k(const float* __restrict__ PS,
                                                const float* __restrict__ PQ,
                                                float* __restrict__ mu,
                                                float* __restrict__ var, int Rows,
                                                int Cols, int nchunk) {
  int c = blockIdx.x * 256 + threadIdx.x;
  if (c >= Cols) return;
  float s = 0.f, q = 0.f;
  for (int z = 0; z < nchunk; ++z) {
    s += PS[(long)z * Cols + c];
    q += PQ[(long)z * Cols + c];
  }
  float m = s / Rows;
  mu[c] = m;
  var[c] = q / Rows - m * m;
}

__global__ void bn_apply2_k(float* __restrict__ X, const float* __restrict__ mu,
                            const float* __restrict__ var, const float* __restrict__ g,
                            const float* __restrict__ b, ushort_t* __restrict__ XB16,
                            int Rows, int Cols) {
  long idx = (long)blockIdx.x * 256 + threadIdx.x;
  if (idx >= (long)Rows * Cols) return;
  int c = (int)(idx % Cols);
  float v = (X[idx] - mu[c]) / sqrtf(var[c] + 1e-5f) * g[c] + b[c];
  X[idx] = v;
  XB16[idx] = f2bf(v);
}

__global__ __launch_bounds__(64) void ff2_k(const ushort_t* __restrict__ Z,
                                            const float* __restrict__ W2,
                                            const float* __restrict__ b2,
                                            float* __restrict__ alpha,
                                            float* __restrict__ beta, int K) {
  int row = blockIdx.x;
  int t = threadIdx.x;
  float s0 = 0.f, s1 = 0.f;
  for (int k = t; k < K; k += 64) {
    float z = bf2f(Z[(long)row * K + k]);
    s0 += z * W2[2 * k];
    s1 += z * W2[2 * k + 1];
  }
  for (int off = 32; off > 0; off >>= 1) {
    s0 += __shfl_down(s0, off);
    s1 += __shfl_down(s1, off);
  }
  if (t == 0) {
    alpha[row] = 1.f / (1.f + expf(-(s0 + b2[0])));
    beta[row] = 1.f / (1.f + expf(-(s1 + b2[1])));
  }
}

// ---------------- branch driver ----------------
template <int KP>
static void run_branch(const float* x, const int* ei, const int* bat,
                       const float* wc1, const float* bc1, const float* wc2,
                       const float* bc2, const float* fgw1, const float* fgb1,
                       const float* fgw2, const float* fgb2, const float* fgg,
                       const float* fgbt, const float* ffw1, const float* ffb1,
                       const float* ffw2, const float* ffb2, int N, int F,
                       float* out_alpha, float* out_beta, float* out_xg,
                       ushort_t* XB, ushort_t* XA, ushort_t* H, ushort_t* WT,
                       int* rowstart, int* BC, int* boff, int* adj, int* GS,
                       float* POOL, float* CM, float* MU, float* VAR, float* SSQ,
                       float* PSUM, float* PSQ, ushort_t* POOLB, ushort_t* WTF1,
                       ushort_t* WTF2, ushort_t* WTFF, ushort_t* G1B, ushort_t* XGB,
                       ushort_t* Z1B, float* PART, hipStream_t stream) {
  const int NC = F * 10;
  const int Bn = NGRAPH;
  const int* src = ei;
  const int* dst = ei + EDGES;
  const int MB = (N + 63) / 64;
  const int Mpad = MB * 64;
  const int NB = (N + 255) >> 8;

  // CSR build (bucketed, LDS-local; EB aliases XB which is rewritten later)
  int2* EB = (int2*)XB;
  int* bcnt = BC;
  int* bcur = BC + NBMAX;
  hipMemsetAsync(BC, 0, 2 * NBMAX * 4, stream);
  bcount_k<<<(EDGES + 4095) / 4096, 256, 0, stream>>>(dst, bcnt, EDGES, NB);
  bscan_k<<<1, 512, 0, stream>>>(bcnt, boff, NB);
  bscatter_k<<<(EDGES + 4095) / 4096, 256, 0, stream>>>(src, dst, boff, bcur, EB, EDGES, NB);
  bucket_csr_k<<<NB, 256, 0, stream>>>(EB, boff, rowstart, adj, N, NB, EDGES);
  gstart_k<<<(NGRAPH + 256) / 256, 256, 0, stream>>>(bat, GS, N, NGRAPH);

  constexpr int CH = KP / 8;
  if (Mpad > N)
    hipMemsetAsync(XA + (size_t)N * KP, 0, (size_t)(Mpad - N) * KP * 2, stream);
  tobf16_k<KP><<<(int)(((long)N * KP + 255) / 256), 256, 0, stream>>>(x, XB, N, F);
  // conv1
  gather_k<KP><<<(int)(((long)N * CH + 255) / 256), 256, 0, stream>>>(XB, rowstart, adj, XA, N);
  wt_k<<<(((F + 63) / 64) * 64 * KP + 255) / 256, 256, 0, stream>>>(
      wc1, WT, F, F, KP, ((F + 63) / 64) * 64);
  conv_gemm2_k<KP><<<MB, 256, 0, stream>>>(XA, WT, bc1, H, N, F, KP, (KP + 63) / 64);
  // conv2 + per-(graph, 2-tile) pool
  gather_k<KP><<<(int)(((long)N * CH + 255) / 256), 256, 0, stream>>>(H, rowstart, adj, XA, N);
  int Npad2 = ((NC + 63) / 64) * 64;
  wt_k<<<(Npad2 * KP + 255) / 256, 256, 0, stream>>>(wc2, WT, F, NC, KP, Npad2);
  int NT2 = Npad2 / 64;
  conv_pool2_k<KP><<<dim3(NGRAPH, (NT2 + 1) / 2), 64, 0, stream>>>(XA, WT, bc2, GS,
                                                                   POOL, NC, NC, NT2);

  // pairnorm stats (two-stage)
  int Cols = 2 * NC;
  const int NCH = 16, CR = NGRAPH / NCH;
  hipMemsetAsync(SSQ, 0, 8, stream);
  colstat_part_k<<<dim3((Cols + 63) / 64, NCH), 256, 0, stream>>>(POOL, PSUM, SSQ, Bn, Cols, CR);
  colstat_fin_k<<<(Cols + 255) / 256, 256, 0, stream>>>(PSUM, CM, Bn, Cols, NCH);
  pn_scale_k<<<1, 256, 0, stream>>>(CM, SSQ, SSQ + 1, Bn, Cols);

  // ---- FC stack: bf16 MFMA split-K ----
  int KP1 = ((Cols + 127) / 128) * 128;
  pn_apply2_k<<<(int)(((long)Bn * KP1 + 255) / 256), 256, 0, stream>>>(
      POOL, CM, SSQ + 1, POOLB, Bn, Cols, KP1);
  wt_k<<<(1024 * KP1 + 255) / 256, 256, 0, stream>>>(fgw1, WTF1, Cols, 1024, KP1, 1024);
  fc_mfma_k<<<dim3(16, 16, 4), 256, 0, stream>>>(POOLB, WTF1, PART, KP1, 1024, KP1 / 4);
  sk_epi2_k<<<(Bn * 1024 + 255) / 256, 256, 0, stream>>>(PART, fgb1, nullptr, G1B, Bn, 1024, 4, 1);
  wt_k<<<(512 * 1024 + 255) / 256, 256, 0, stream>>>(fgw2, WTF2, 1024, 512, 1024, 512);
  fc_mfma_k<<<dim3(8, 16, 4), 256, 0, stream>>>(G1B, WTF2, PART, 1024, 512, 256);
  sk_epi2_k<<<(Bn * 512 + 255) / 256, 256, 0, stream>>>(PART, fgb2, out_xg, nullptr, Bn, 512, 4, 0);
  bn_part_k<<<dim3(8, 8), 256, 0, stream>>>(out_xg, PSUM, PSQ, Bn, 512, 128);
  bn_fin_k<<<2, 256, 0, stream>>>(PSUM, PSQ, MU, VAR, Bn, 512, 8);
  bn_apply2_k<<<(Bn * 512 + 255) / 256, 256, 0, stream>>>(out_xg, MU, VAR, fgg, fgbt, XGB, Bn, 512);
  wt_k<<<(256 * 512 + 255) / 256, 256, 0, stream>>>(ffw1, WTFF, 512, 256, 512, 256);
  fc_mfma_k<<<dim3(4, 16, 8), 256, 0, stream>>>(XGB, WTFF, PART, 512, 256, 64);
  sk_epi2_k<<<(Bn * 256 + 255) / 256, 256, 0, stream>>>(PART, ffb1, nullptr, Z1B, Bn, 256, 8, 1);
  ff2_k<<<Bn, 64, 0, stream>>>(Z1B, ffw2, ffb2, out_alpha, out_beta, 256);
}

extern "C" void kernel_launch(void* const* d_in, const int* in_sizes, int n_in,
                              void* d_out, int out_size, void* d_ws, size_t ws_size,
                              hipStream_t stream) {
  if (n_in < 34) return;
  const float* x0 = (const float*)d_in[0];
  const int* ei0 = (const int*)d_in[1];
  const int* b0 = (const int*)d_in[2];
  const float* x1 = (const float*)d_in[3];
  const int* ei1 = (const int*)d_in[4];
  const int* b1 = (const int*)d_in[5];
  const float* w_c1 = (const float*)d_in[6];
  const float* b_c1 = (const float*)d_in[7];
  const float* w_c2 = (const float*)d_in[8];
  const float* b_c2 = (const float*)d_in[9];
  const float* w_c3 = (const float*)d_in[10];
  const float* b_c3 = (const float*)d_in[11];
  const float* w_c4 = (const float*)d_in[12];
  const float* b_c4 = (const float*)d_in[13];
  const float* fg0_w1 = (const float*)d_in[14];
  const float* fg0_b1 = (const float*)d_in[15];
  const float* fg0_w2 = (const float*)d_in[16];
  const float* fg0_b2 = (const float*)d_in[17];
  const float* fg0_g = (const float*)d_in[18];
  const float* fg0_bt = (const float*)d_in[19];
  const float* fg1_w1 = (const float*)d_in[20];
  const float* fg1_b1 = (const float*)d_in[21];
  const float* fg1_w2 = (const float*)d_in[22];
  const float* fg1_b2 = (const float*)d_in[23];
  const float* fg1_g = (const float*)d_in[24];
  const float* fg1_bt = (const float*)d_in[25];
  const float* ff0_w1 = (const float*)d_in[26];
  const float* ff0_b1 = (const float*)d_in[27];
  const float* ff0_w2 = (const float*)d_in[28];
  const float* ff0_b2 = (const float*)d_in[29];
  const float* ff1_w1 = (const float*)d_in[30];
  const float* ff1_b1 = (const float*)d_in[31];
  const float* ff1_w2 = (const float*)d_in[32];
  const float* ff1_b2 = (const float*)d_in[33];

  float* out = (float*)d_out;
  float* alpha = out;
  float* beta = out + 1024;
  float* xg0 = out + 2048;
  float* xg1 = out + 2048 + 1024 * 512;
  float* alpha1 = out + 2048 + 2 * 1024 * 512;
  float* beta1 = alpha1 + 1024;

  char* w = (char*)d_ws;
  auto alloc = [&](size_t bytes) -> void* {
    void* p = (void*)w;
    w += ((bytes + 255) / 256) * 256;
    return p;
  };
  const int Mpad = ((NNODES + 63) / 64) * 64;
  ushort_t* XB = (ushort_t*)alloc((size_t)Mpad * 96 * 2);
  ushort_t* XA = (ushort_t*)alloc((size_t)Mpad * 96 * 2);
  ushort_t* H = (ushort_t*)alloc((size_t)Mpad * 96 * 2);
  ushort_t* WT = (ushort_t*)alloc((size_t)960 * 96 * 2);
  int* rowstart = (int*)alloc((size_t)(NNODES + 1) * 4);
  int* BC = (int*)alloc(2 * NBMAX * 4);
  int* boff = (int*)alloc((NBMAX + 1) * 4);
  int* adj = (int*)alloc((size_t)EDGES * 4);
  int* GS = (int*)alloc((size_t)(NGRAPH + 1) * 4);
  float* POOL = (float*)alloc((size_t)NGRAPH * 1860 * 4);
  float* CM = (float*)alloc(1860 * 4);
  float* MU = (float*)alloc(512 * 4);
  float* VAR = (float*)alloc(512 * 4);
  float* SSQ = (float*)alloc(256);
  float* PSUM = (float*)alloc((size_t)16 * 1920 * 4);
  float* PSQ = (float*)alloc((size_t)8 * 512 * 4);
  ushort_t* POOLB = (ushort_t*)alloc((size_t)NGRAPH * 1920 * 2);
  ushort_t* WTF1 = (ushort_t*)alloc((size_t)1024 * 1920 * 2);
  ushort_t* WTF2 = (ushort_t*)alloc((size_t)512 * 1024 * 2);
  ushort_t* WTFF = (ushort_t*)alloc((size_t)256 * 512 * 2);
  ushort_t* G1B = (ushort_t*)alloc((size_t)NGRAPH * 1024 * 2);
  ushort_t* XGB = (ushort_t*)alloc((size_t)NGRAPH * 512 * 2);
  ushort_t* Z1B = (ushort_t*)alloc((size_t)NGRAPH * 256 * 2);
  if ((size_t)(w - (char*)d_ws) > ws_size) return;

  float* PART = (float*)XB;

  run_branch<96>(x0, ei0, b0, w_c1, b_c1, w_c2, b_c2, fg0_w1, fg0_b1, fg0_w2,
                 fg0_b2, fg0_g, fg0_bt, ff0_w1, ff0_b1, ff0_w2, ff0_b2, NNODES,
                 93, alpha, beta, xg0, XB, XA, H, WT, rowstart, BC, boff, adj, GS,
                 POOL, CM, MU, VAR, SSQ, PSUM, PSQ, POOLB, WTF1, WTF2, WTFF, G1B,
                 XGB, Z1B, PART, stream);
  run_branch<64>(x1, ei1, b1, w_c3, b_c3, w_c4, b_c4, fg1_w1, fg1_b1, fg1_w2,
                 fg1_b2, fg1_g, fg1_bt, ff1_w1, ff1_b1, ff1_w2, ff1_b2, NNODES,
                 43, alpha1, beta1, xg1, XB, XA, H, WT, rowstart, BC, boff, adj,
                 GS, POOL, CM, MU, VAR, SSQ, PSUM, PSQ, POOLB, WTF1, WTF2, WTFF,
                 G1B, XGB, Z1B, PART, stream);
}